// Round 1
// baseline (26600.256 us; speedup 1.0000x reference)
//
#include <hip/hip_runtime.h>
#include <math.h>

#define B 8192
#define T 20
#define NF 812
#define HID 400
#define NG 1600   // 4*HID
#define VARI 811
#define KTOT (NF + 1 + HID)  // 1213

#define BB 64   // batch tile
#define HH 16   // hidden tile (x4 gates -> 64 gate cols)
#define KC 16   // K chunk

// ---------------------------------------------------------------------------
// prep: w_sum[j] = sum_k W_decay[j][k]; bias[i] = b_ih[i]+b_hh[i];
//       den[t] = sum_b masks[b][t]
// ---------------------------------------------------------------------------
__global__ void prep_kernel(const float* __restrict__ W_decay,
                            const float* __restrict__ b_ih,
                            const float* __restrict__ b_hh,
                            const float* __restrict__ masks,
                            float* __restrict__ wsum,
                            float* __restrict__ bias,
                            float* __restrict__ den) {
    int blk = blockIdx.x;
    int lane = threadIdx.x;  // 64 threads
    if (blk < HID) {
        float s = 0.f;
        for (int k = lane; k < NF; k += 64) s += W_decay[blk * NF + k];
        for (int o = 32; o; o >>= 1) s += __shfl_down(s, o);
        if (lane == 0) wsum[blk] = s;
    } else if (blk < HID + 25) {
        int i = (blk - HID) * 64 + lane;
        if (i < NG) bias[i] = b_ih[i] + b_hh[i];
    } else {
        int t = blk - HID - 25;
        if (t < T) {
            float s = 0.f;
            for (int b = lane; b < B; b += 64) s += masks[b * T + t];
            for (int o = 32; o; o >>= 1) s += __shfl_down(s, o);
            if (lane == 0) den[t] = s;
        }
    }
}

// ---------------------------------------------------------------------------
// decay + imputation: one wave per batch row.
//   gamma = exp(-relu(d*wsum + b_decay)); h *= gamma (in place, elementwise)
//   x_h = h . W_reg + b_reg ; x_var = x[811]*m + (1-m)*x_h
// ---------------------------------------------------------------------------
__global__ void decay_impute_kernel(int t,
                                    const float* __restrict__ values,
                                    const float* __restrict__ masks,
                                    const float* __restrict__ deltas,
                                    const float* __restrict__ b_decay,
                                    const float* __restrict__ W_reg,
                                    const float* __restrict__ b_reg,
                                    const float* __restrict__ wsum,
                                    float* __restrict__ h,
                                    float* __restrict__ xvar,
                                    float* __restrict__ num,
                                    float* __restrict__ out_imp) {
    int wave = threadIdx.x >> 6;
    int lane = threadIdx.x & 63;
    int b = blockIdx.x * 4 + wave;
    float d = deltas[b * T + t];
    float m = masks[b * T + t];
    float dot = 0.f;
    for (int j = lane; j < HID; j += 64) {
        float g = expf(-fmaxf(fmaf(d, wsum[j], b_decay[j]), 0.f));
        float hv = h[b * HID + j] * g;
        h[b * HID + j] = hv;
        dot = fmaf(hv, W_reg[j], dot);
    }
    for (int o = 32; o; o >>= 1) dot += __shfl_down(dot, o);
    if (lane == 0) {
        float x_h = dot + b_reg[0];
        float xv = values[(size_t)(b * T + t) * NF + VARI];
        float x_var = xv * m + (1.f - m) * x_h;
        out_imp[b * T + t] = x_var;
        xvar[b] = x_var;
        if (m != 0.f) atomicAdd(&num[t], fabsf(x_var - x_h));
    }
}

// ---------------------------------------------------------------------------
// fused gates GEMM + LSTM cell.
//   gates[b][g*400+j] = sum_k A[b][k]*Bmat[g*400+j][k] + bias
//   A[b][k] = values (k<811) | xvar (k=811) | mask (k=812) | h_in (k>=813)
//   Bmat row r: W_ih[r][k] (k<813) | W_hh[r][k-813]
// tile: 64 batch x 16 hidden x 4 gates; thread owns 4 batch x 1 hidden x 4 gates
// ---------------------------------------------------------------------------
__global__ __launch_bounds__(256)
void step_kernel(int t,
                 const float* __restrict__ values,
                 const float* __restrict__ masks,
                 const float* __restrict__ W_ih,
                 const float* __restrict__ W_hh,
                 const float* __restrict__ bias,
                 const float* __restrict__ xvar,
                 const float* __restrict__ h_in,
                 float* __restrict__ h_out,
                 float* __restrict__ c) {
    __shared__ float As[BB][KC + 1];
    __shared__ float Bs[4][HH][KC + 1];
    int tid = threadIdx.x;
    int hh = tid & 15;
    int bq = tid >> 4;        // 0..15
    int b0 = blockIdx.x * BB;
    int j0 = blockIdx.y * HH;

    float acc[4][4] = {{0.f}};

    for (int kc0 = 0; kc0 < KTOT; kc0 += KC) {
        // stage A chunk: 64 rows x 16 k, coalesced over k
        {
            int kk = tid & 15;
            int k = kc0 + kk;
#pragma unroll
            for (int i = 0; i < 4; i++) {
                int bb = i * 16 + (tid >> 4);
                int b = b0 + bb;
                float v;
                if (k < VARI)            v = values[(size_t)(b * T + t) * NF + k];
                else if (k == VARI)      v = xvar[b];
                else if (k == NF)        v = masks[b * T + t];
                else if (k < KTOT)       v = h_in[b * HID + (k - NF - 1)];
                else                     v = 0.f;
                As[bb][kk] = v;
            }
        }
        // stage B chunk: 4 gates x 16 hidden x 16 k, coalesced over k
        {
            int kk = tid & 15;
            int h2 = tid >> 4;  // 0..15
            int k = kc0 + kk;
#pragma unroll
            for (int g = 0; g < 4; g++) {
                int r = g * HID + j0 + h2;
                float v;
                if (k < NF + 1)     v = W_ih[(size_t)r * (NF + 1) + k];
                else if (k < KTOT)  v = W_hh[(size_t)r * HID + (k - NF - 1)];
                else                v = 0.f;
                Bs[g][h2][kk] = v;
            }
        }
        __syncthreads();
#pragma unroll
        for (int kk = 0; kk < KC; kk++) {
            float av[4];
#pragma unroll
            for (int bi = 0; bi < 4; bi++) av[bi] = As[bq * 4 + bi][kk];
#pragma unroll
            for (int g = 0; g < 4; g++) {
                float wv = Bs[g][hh][kk];
#pragma unroll
                for (int bi = 0; bi < 4; bi++)
                    acc[g][bi] = fmaf(av[bi], wv, acc[g][bi]);
            }
        }
        __syncthreads();
    }

    // epilogue: LSTM cell
    int j = j0 + hh;
    float bi_i = bias[j];
    float bi_f = bias[HID + j];
    float bi_g = bias[2 * HID + j];
    float bi_o = bias[3 * HID + j];
#pragma unroll
    for (int bi = 0; bi < 4; bi++) {
        int b = b0 + bq * 4 + bi;
        float i_g = acc[0][bi] + bi_i;
        float f_g = acc[1][bi] + bi_f;
        float g_g = acc[2][bi] + bi_g;
        float o_g = acc[3][bi] + bi_o;
        float si = 1.f / (1.f + expf(-i_g));
        float sf = 1.f / (1.f + expf(-f_g));
        float so = 1.f / (1.f + expf(-o_g));
        float cg = tanhf(g_g);
        size_t idx = (size_t)b * HID + j;
        float cn = sf * c[idx] + si * cg;
        c[idx] = cn;
        h_out[idx] = so * tanhf(cn);
    }
}

__global__ void finalize_kernel(const float* __restrict__ num,
                                const float* __restrict__ den,
                                float* __restrict__ out) {
    if (threadIdx.x == 0) {
        float s = 0.f;
        for (int t = 0; t < T; t++) s += num[t] / (den[t] + 1e-5f);
        out[0] = s / (float)T;
    }
}

extern "C" void kernel_launch(void* const* d_in, const int* in_sizes, int n_in,
                              void* d_out, int out_size, void* d_ws, size_t ws_size,
                              hipStream_t stream) {
    const float* values  = (const float*)d_in[0];
    const float* masks   = (const float*)d_in[1];
    const float* deltas  = (const float*)d_in[2];
    const float* W_decay = (const float*)d_in[3];
    const float* b_decay = (const float*)d_in[4];
    const float* W_reg   = (const float*)d_in[5];
    const float* b_reg   = (const float*)d_in[6];
    const float* W_ih    = (const float*)d_in[7];
    const float* W_hh    = (const float*)d_in[8];
    const float* b_ih    = (const float*)d_in[9];
    const float* b_hh    = (const float*)d_in[10];

    float* out = (float*)d_out;
    float* ws  = (float*)d_ws;

    const size_t BH = (size_t)B * HID;
    float* h0   = ws;            // BH
    float* c    = ws + BH;       // BH (adjacent to h0 -> one memset)
    float* h1   = ws + 2 * BH;   // BH
    float* xvar = ws + 3 * BH;   // B
    float* wsum = xvar + B;      // 512 slot
    float* bias = wsum + 512;    // NG
    float* num  = bias + NG;     // 32
    float* den  = num + 32;      // 32

    // zero h0 + c (contiguous), and the per-step loss numerators
    hipMemsetAsync(h0, 0, 2 * BH * sizeof(float), stream);
    hipMemsetAsync(num, 0, 32 * sizeof(float), stream);

    prep_kernel<<<HID + 25 + T, 64, 0, stream>>>(W_decay, b_ih, b_hh, masks,
                                                 wsum, bias, den);

    for (int t = 0; t < T; t++) {
        float* hin  = (t & 1) ? h1 : h0;
        float* hout = (t & 1) ? h0 : h1;
        decay_impute_kernel<<<B / 4, 256, 0, stream>>>(
            t, values, masks, deltas, b_decay, W_reg, b_reg, wsum,
            hin, xvar, num, out + 1);
        dim3 grid(B / BB, HID / HH);
        step_kernel<<<grid, 256, 0, stream>>>(
            t, values, masks, W_ih, W_hh, bias, xvar, hin, hout, c);
    }

    finalize_kernel<<<1, 64, 0, stream>>>(num, den, out);
}

// Round 2
// 3467.460 us; speedup vs baseline: 7.6714x; 7.6714x over previous
//
#include <hip/hip_runtime.h>
#include <math.h>

#define B 8192
#define T 20
#define NF 812
#define HID 400
#define NG 1600          // 4*HID
#define VARI 811
#define KP 832           // padded K for pre GEMM (813 used, rest 0)
#define KPC 26           // KP/32
#define KH 416           // padded K for h GEMM (400 used)
#define KHC 13           // KH/32
#define BM 128
#define BN 64
#define MROWS (B * T)    // 163840

typedef __attribute__((ext_vector_type(8))) short short8;
typedef __attribute__((ext_vector_type(4))) short short4v;
typedef __attribute__((ext_vector_type(4))) unsigned short ushort4v;
typedef __attribute__((ext_vector_type(4))) float floatx4;

__device__ inline short f2bf(float f) {
    union { float f; unsigned u; } v; v.f = f;
    unsigned r = v.u + 0x7FFF + ((v.u >> 16) & 1);
    return (short)(r >> 16);
}
__device__ inline float bf2f(unsigned short s) {
    union { float f; unsigned u; } v; v.u = ((unsigned)s) << 16;
    return v.f;
}
__device__ inline void glds16(const void* g, void* l) {
    __builtin_amdgcn_global_load_lds(
        (const __attribute__((address_space(1))) void*)g,
        (__attribute__((address_space(3))) void*)l, 16, 0, 0);
}
__device__ inline float sigm(float x) { return 1.f / (1.f + expf(-x)); }

// ---------------------------------------------------------------------------
// prep: wsum[j] = sum_k W_decay[j][k] ; den[t] = sum_b masks[b][t]
// ---------------------------------------------------------------------------
__global__ void prep_kernel(const float* __restrict__ W_decay,
                            const float* __restrict__ masks,
                            float* __restrict__ wsum,
                            float* __restrict__ den) {
    int blk = blockIdx.x;
    int lane = threadIdx.x;
    if (blk < HID) {
        float s = 0.f;
        for (int k = lane; k < NF; k += 64) s += W_decay[blk * NF + k];
        for (int o = 32; o; o >>= 1) s += __shfl_down(s, o);
        if (lane == 0) wsum[blk] = s;
    } else {
        int t = blk - HID;
        if (t < T) {
            float s = 0.f;
            for (int b = lane; b < B; b += 64) s += masks[b * T + t];
            for (int o = 32; o; o >>= 1) s += __shfl_down(s, o);
            if (lane == 0) den[t] = s;
        }
    }
}

// ---------------------------------------------------------------------------
// conv_inp: Inp_bf16[row][k], row = b*T+t, k<811: values, 811: 0, 812: mask,
// 813..831: 0.  One block per row; thread t handles cols 4t..4t+3 (t<208).
// ---------------------------------------------------------------------------
__global__ void conv_inp(const float* __restrict__ values,
                         const float* __restrict__ masks,
                         short* __restrict__ Inpb) {
    int row = blockIdx.x;
    int t = threadIdx.x;
    if (t >= 208) return;
    short4v o;
    if (t < 202) {
        const float4* src = (const float4*)(values + (size_t)row * NF + 4 * t);
        float4 v = *src;
        o.x = f2bf(v.x); o.y = f2bf(v.y); o.z = f2bf(v.z); o.w = f2bf(v.w);
    } else if (t == 202) {  // cols 808..811 ; 811 -> 0
        const float4* src = (const float4*)(values + (size_t)row * NF + 808);
        float4 v = *src;
        o.x = f2bf(v.x); o.y = f2bf(v.y); o.z = f2bf(v.z); o.w = 0;
    } else if (t == 203) {  // cols 812..815 : mask,0,0,0
        o.x = f2bf(masks[row]); o.y = 0; o.z = 0; o.w = 0;
    } else {
        o.x = o.y = o.z = o.w = 0;
    }
    *(short4v*)(Inpb + (size_t)row * KP + 4 * t) = o;
}

// ---------------------------------------------------------------------------
// conv_wih: reorder W_ih rows r'=j*4+g <- r=g*400+j, pad K to 832, bf16.
// Also w811r[r'] = W_ih[r][811] (fp32), biasr[r'] = b_ih[r]+b_hh[r].
// ---------------------------------------------------------------------------
__global__ void conv_wih(const float* __restrict__ W_ih,
                         const float* __restrict__ b_ih,
                         const float* __restrict__ b_hh,
                         short* __restrict__ Wihb,
                         float* __restrict__ w811r,
                         float* __restrict__ biasr) {
    int rp = blockIdx.x;          // 0..1599
    int j = rp >> 2, g = rp & 3;
    int r = g * HID + j;
    int t = threadIdx.x;
    if (t < 208) {
        short4v o;
#pragma unroll
        for (int i = 0; i < 4; i++) {
            int k = 4 * t + i;
            float v = (k < NF + 1) ? W_ih[(size_t)r * (NF + 1) + k] : 0.f;
            ((short*)&o)[i] = f2bf(v);
        }
        *(short4v*)(Wihb + (size_t)rp * KP + 4 * t) = o;
    } else if (t == 255) {
        w811r[rp] = W_ih[(size_t)r * (NF + 1) + VARI];
        biasr[rp] = b_ih[r] + b_hh[r];
    }
}

// conv_whh: reorder W_hh rows, pad K 400->416, bf16.
__global__ void conv_whh(const float* __restrict__ W_hh,
                         short* __restrict__ Whhb) {
    int rp = blockIdx.x;
    int j = rp >> 2, g = rp & 3;
    int r = g * HID + j;
    int t = threadIdx.x;
    if (t >= 104) return;
    short4v o;
#pragma unroll
    for (int i = 0; i < 4; i++) {
        int k = 4 * t + i;
        float v = (k < HID) ? W_hh[(size_t)r * HID + k] : 0.f;
        ((short*)&o)[i] = f2bf(v);
    }
    *(short4v*)(Whhb + (size_t)rp * KH + 4 * t) = o;
}

// ---------------------------------------------------------------------------
// pre_gemm: pre[row][n] = Inp[row][:] . Wihb[n][:] + biasr[n]   (bf16 out)
// M=163840, N=1600, K=832.  BM=128, BN=64, 256 thr / 4 waves, wave tile 64x32.
// ---------------------------------------------------------------------------
__global__ __launch_bounds__(256)
void pre_gemm(const short* __restrict__ Inpb,
              const short* __restrict__ Wihb,
              const float* __restrict__ biasr,
              short* __restrict__ preb) {
    __shared__ __align__(16) short As[BM * 32];
    __shared__ __align__(16) short Bs[BN * 32];
    int tid = threadIdx.x;
    int lane = tid & 63;
    int wave = tid >> 6;
    int row0 = blockIdx.y * BM;
    int n0 = blockIdx.x * BN;
    int wm = wave & 1, wn = wave >> 1;
    int q = lane >> 4;      // 16B slot within K-chunk
    int mr = lane & 15;

    floatx4 acc[4][2] = {};

    const char* Ag = (const char*)(Inpb + (size_t)row0 * KP);
    const char* Bg = (const char*)(Wihb + (size_t)n0 * KP);

    for (int kc = 0; kc < KPC; kc++) {
        int kbyte = kc * 64;
#pragma unroll
        for (int i = 0; i < 2; i++) {
            int r = i * 64 + wave * 16 + (lane >> 2);
            glds16(Ag + (size_t)r * (KP * 2) + kbyte + (lane & 3) * 16,
                   (char*)As + (i * 64 + wave * 16) * 64);
        }
        {
            int r = wave * 16 + (lane >> 2);
            glds16(Bg + (size_t)r * (KP * 2) + kbyte + (lane & 3) * 16,
                   (char*)Bs + (wave * 16) * 64);
        }
        __syncthreads();
        const short8* Av = (const short8*)As;
        const short8* Bv = (const short8*)Bs;
        short8 a[4], b[2];
#pragma unroll
        for (int f = 0; f < 4; f++) a[f] = Av[(wm * 64 + f * 16 + mr) * 4 + q];
#pragma unroll
        for (int f = 0; f < 2; f++) b[f] = Bv[(wn * 32 + f * 16 + mr) * 4 + q];
#pragma unroll
        for (int f = 0; f < 4; f++)
#pragma unroll
            for (int g = 0; g < 2; g++)
                acc[f][g] = __builtin_amdgcn_mfma_f32_16x16x32_bf16(a[f], b[g], acc[f][g], 0, 0, 0);
        __syncthreads();
    }
#pragma unroll
    for (int f = 0; f < 4; f++)
#pragma unroll
        for (int g = 0; g < 2; g++) {
            int n = wn * 32 + g * 16 + mr;
            float bia = biasr[n0 + n];
#pragma unroll
            for (int r = 0; r < 4; r++) {
                int m = wm * 64 + f * 16 + q * 4 + r;
                preb[(size_t)(row0 + m) * NG + n0 + n] = f2bf(acc[f][g][r] + bia);
            }
        }
}

// ---------------------------------------------------------------------------
// decay + imputation.  Block = 4 waves, 8 rows/wave -> 32 rows/block.
// h (fp32) *= gamma in place; also writes h_bf16 (padded to 416).
// ---------------------------------------------------------------------------
__global__ __launch_bounds__(256)
void decay_impute(int t,
                  const float* __restrict__ values,
                  const float* __restrict__ masks,
                  const float* __restrict__ deltas,
                  const float* __restrict__ b_decay,
                  const float* __restrict__ W_reg,
                  const float* __restrict__ b_reg,
                  const float* __restrict__ wsum,
                  float* __restrict__ h,
                  short* __restrict__ hbf,
                  float* __restrict__ xvar,
                  float* __restrict__ num,
                  float* __restrict__ out_imp) {
    int wave = threadIdx.x >> 6;
    int lane = threadIdx.x & 63;
    int bbase = blockIdx.x * 32 + wave * 8;
    float lnum = 0.f;
    for (int i = 0; i < 8; i++) {
        int b = bbase + i;
        float d = deltas[b * T + t];
        float m = masks[b * T + t];
        float dot = 0.f;
        for (int j = lane; j < HID; j += 64) {
            float g = expf(-fmaxf(fmaf(d, wsum[j], b_decay[j]), 0.f));
            float hv = h[(size_t)b * HID + j] * g;
            h[(size_t)b * HID + j] = hv;
            hbf[(size_t)b * KH + j] = f2bf(hv);
            dot = fmaf(hv, W_reg[j], dot);
        }
        if (lane < 16) hbf[(size_t)b * KH + HID + lane] = 0;
        for (int o = 32; o; o >>= 1) dot += __shfl_down(dot, o);
        if (lane == 0) {
            float x_h = dot + b_reg[0];
            float xv = values[(size_t)(b * T + t) * NF + VARI];
            float x_var = xv * m + (1.f - m) * x_h;
            out_imp[b * T + t] = x_var;
            xvar[b] = x_var;
            if (m != 0.f) lnum += fabsf(x_var - x_h);
        }
    }
    if (lane == 0) atomicAdd(&num[t], lnum);
}

// ---------------------------------------------------------------------------
// step_gemm: gates = hbf @ Whhb^T (MFMA) ; epilogue adds pre + xvar*w811,
// applies LSTM cell, writes c and h_out (fp32).
// N-tile of 64 = 16 hidden units x 4 gates (reordered rows).
// ---------------------------------------------------------------------------
__global__ __launch_bounds__(256)
void step_gemm(int t,
               const short* __restrict__ hbf,
               const short* __restrict__ Whhb,
               const short* __restrict__ preb,
               const float* __restrict__ w811r,
               const float* __restrict__ xvar,
               float* __restrict__ c,
               float* __restrict__ h_out) {
    __shared__ __align__(16) short As[BM * 32];
    __shared__ __align__(16) short Bs[BN * 32];
    __shared__ float gt[BM * BN];
    int tid = threadIdx.x;
    int lane = tid & 63;
    int wave = tid >> 6;
    int b0 = blockIdx.y * BM;
    int n0 = blockIdx.x * BN;
    int wm = wave & 1, wn = wave >> 1;
    int q = lane >> 4;
    int mr = lane & 15;

    floatx4 acc[4][2] = {};

    const char* Ag = (const char*)(hbf + (size_t)b0 * KH);
    const char* Bg = (const char*)(Whhb + (size_t)n0 * KH);

    for (int kc = 0; kc < KHC; kc++) {
        int kbyte = kc * 64;
#pragma unroll
        for (int i = 0; i < 2; i++) {
            int r = i * 64 + wave * 16 + (lane >> 2);
            glds16(Ag + (size_t)r * (KH * 2) + kbyte + (lane & 3) * 16,
                   (char*)As + (i * 64 + wave * 16) * 64);
        }
        {
            int r = wave * 16 + (lane >> 2);
            glds16(Bg + (size_t)r * (KH * 2) + kbyte + (lane & 3) * 16,
                   (char*)Bs + (wave * 16) * 64);
        }
        __syncthreads();
        const short8* Av = (const short8*)As;
        const short8* Bv = (const short8*)Bs;
        short8 a[4], b[2];
#pragma unroll
        for (int f = 0; f < 4; f++) a[f] = Av[(wm * 64 + f * 16 + mr) * 4 + q];
#pragma unroll
        for (int f = 0; f < 2; f++) b[f] = Bv[(wn * 32 + f * 16 + mr) * 4 + q];
#pragma unroll
        for (int f = 0; f < 4; f++)
#pragma unroll
            for (int g = 0; g < 2; g++)
                acc[f][g] = __builtin_amdgcn_mfma_f32_16x16x32_bf16(a[f], b[g], acc[f][g], 0, 0, 0);
        __syncthreads();
    }
    // dump accumulators to LDS gate tile
#pragma unroll
    for (int f = 0; f < 4; f++)
#pragma unroll
        for (int g = 0; g < 2; g++) {
            int n = wn * 32 + g * 16 + mr;
#pragma unroll
            for (int r = 0; r < 4; r++) {
                int m = wm * 64 + f * 16 + q * 4 + r;
                gt[m * BN + n] = acc[f][g][r];
            }
        }
    __syncthreads();

    // LSTM cell: thread -> (jj = tid&15, bb = tid>>4 + 16*i)
    int jj = tid & 15;
    int bb0 = tid >> 4;
    int j = blockIdx.x * 16 + jj;
    float w0 = w811r[n0 + jj * 4 + 0];
    float w1 = w811r[n0 + jj * 4 + 1];
    float w2 = w811r[n0 + jj * 4 + 2];
    float w3 = w811r[n0 + jj * 4 + 3];
#pragma unroll
    for (int i = 0; i < 8; i++) {
        int bb = bb0 + i * 16;
        int b = b0 + bb;
        float xv = xvar[b];
        ushort4v pv = *(const ushort4v*)(preb + ((size_t)b * T + t) * NG + n0 + jj * 4);
        float gi = gt[bb * BN + jj * 4 + 0] + bf2f(pv.x) + xv * w0;
        float gf = gt[bb * BN + jj * 4 + 1] + bf2f(pv.y) + xv * w1;
        float gg = gt[bb * BN + jj * 4 + 2] + bf2f(pv.z) + xv * w2;
        float go = gt[bb * BN + jj * 4 + 3] + bf2f(pv.w) + xv * w3;
        size_t idx = (size_t)b * HID + j;
        float cn = sigm(gf) * c[idx] + sigm(gi) * tanhf(gg);
        c[idx] = cn;
        h_out[idx] = sigm(go) * tanhf(cn);
    }
}

__global__ void finalize_kernel(const float* __restrict__ num,
                                const float* __restrict__ den,
                                float* __restrict__ out) {
    if (threadIdx.x == 0) {
        float s = 0.f;
        for (int t = 0; t < T; t++) s += num[t] / (den[t] + 1e-5f);
        out[0] = s / (float)T;
    }
}

extern "C" void kernel_launch(void* const* d_in, const int* in_sizes, int n_in,
                              void* d_out, int out_size, void* d_ws, size_t ws_size,
                              hipStream_t stream) {
    const float* values  = (const float*)d_in[0];
    const float* masks   = (const float*)d_in[1];
    const float* deltas  = (const float*)d_in[2];
    const float* W_decay = (const float*)d_in[3];
    const float* b_decay = (const float*)d_in[4];
    const float* W_reg   = (const float*)d_in[5];
    const float* b_reg   = (const float*)d_in[6];
    const float* W_ih    = (const float*)d_in[7];
    const float* W_hh    = (const float*)d_in[8];
    const float* b_ih    = (const float*)d_in[9];
    const float* b_hh    = (const float*)d_in[10];
    float* out = (float*)d_out;

    char* p = (char*)d_ws;
    auto alloc = [&](size_t bytes) { char* r = p; p += (bytes + 255) & ~(size_t)255; return r; };
    const size_t BH = (size_t)B * HID;
    float* h0    = (float*)alloc(BH * 4);
    float* c     = (float*)alloc(BH * 4);          // contiguous with h0
    float* h1    = (float*)alloc(BH * 4);
    short* hbf   = (short*)alloc((size_t)B * KH * 2);
    float* xvar  = (float*)alloc(B * 4);
    float* wsum  = (float*)alloc(HID * 4);
    float* w811r = (float*)alloc(NG * 4);
    float* biasr = (float*)alloc(NG * 4);
    float* num   = (float*)alloc(32 * 4);
    float* den   = (float*)alloc(32 * 4);
    short* Wihb  = (short*)alloc((size_t)NG * KP * 2);
    short* Whhb  = (short*)alloc((size_t)NG * KH * 2);
    short* Inpb  = (short*)alloc((size_t)MROWS * KP * 2);
    short* preb  = (short*)alloc((size_t)MROWS * NG * 2);

    hipMemsetAsync(h0, 0, 2 * BH * 4, stream);   // h0 + c
    hipMemsetAsync(num, 0, 32 * 4, stream);

    prep_kernel<<<HID + T, 64, 0, stream>>>(W_decay, masks, wsum, den);
    conv_wih<<<NG, 256, 0, stream>>>(W_ih, b_ih, b_hh, Wihb, w811r, biasr);
    conv_whh<<<NG, 128, 0, stream>>>(W_hh, Whhb);
    conv_inp<<<MROWS, 256, 0, stream>>>(values, masks, Inpb);
    {
        dim3 grid(NG / BN, MROWS / BM);   // x = N tiles (share A slab in L2)
        pre_gemm<<<grid, 256, 0, stream>>>(Inpb, Wihb, biasr, preb);
    }
    for (int t = 0; t < T; t++) {
        float* hin  = (t & 1) ? h1 : h0;
        float* hout = (t & 1) ? h0 : h1;
        decay_impute<<<B / 32, 256, 0, stream>>>(
            t, values, masks, deltas, b_decay, W_reg, b_reg, wsum,
            hin, hbf, xvar, num, out + 1);
        dim3 grid(NG / BN, B / BM);
        step_gemm<<<grid, 256, 0, stream>>>(t, hbf, Whhb, preb, w811r, xvar, c, hout);
    }
    finalize_kernel<<<1, 64, 0, stream>>>(num, den, out);
}